// Round 8
// baseline (191.524 us; speedup 1.0000x reference)
//
#include <hip/hip_runtime.h>
#include <hip/hip_bf16.h>
#include <string.h>

using short8 = __attribute__((ext_vector_type(8))) short;
using f32x4  = __attribute__((ext_vector_type(4))) float;

#define POOLN     9216       // 144*64 elements (bf16) per image
#define FC1N      128
#define WT2_ELEMS 18432      // 36*64*8
#define WT2_BYTES 36864
#define H1S_STRIDE 36        // shorts per position row (72 B): 2-way max conflicts
#define XS_STRIDE  29        // floats per x row (odd -> conflict-free)

#define GLL16(gp, lp) __builtin_amdgcn_global_load_lds( \
    (const __attribute__((address_space(1))) void*)(gp), \
    (__attribute__((address_space(3))) void*)(lp), 16, 0, 0)

static __device__ __forceinline__ unsigned short f2bf(float f) {
  unsigned int u = __builtin_bit_cast(unsigned int, f);
  unsigned int r = (u + 0x7FFFu + ((u >> 16) & 1u)) >> 16;
  return (unsigned short)r;
}

// packed RNE pair convert -> v_cvt_pk_bf16_f32 (compiler-emitted, m240)
static __device__ __forceinline__ unsigned int pkbf(float lo, float hi) {
  __hip_bfloat162 h2 = __float22bfloat162_rn(make_float2(lo, hi));
  unsigned int r;
  memcpy(&r, &h2, sizeof(r));
  return r;
}

// ---- one-off: w2 fp32 [64][32][9] -> wt2 bf16 fragment order [(tap*4+n)][lane][8]
__global__ __launch_bounds__(256) void k_wt2(const float* __restrict__ w2,
    unsigned short* __restrict__ wt2) {
  int idx = blockIdx.x * 256 + threadIdx.x;
  if (idx >= WT2_ELEMS) return;
  int j = idx & 7;
  int l = (idx >> 3) & 63;
  int tn = idx >> 9;            // 0..35
  int tap = tn >> 2, n = tn & 3;
  int oc = n * 16 + (l & 15);
  int ic = (l >> 4) * 8 + j;
  wt2[idx] = f2bf(w2[oc * 288 + ic * 9 + tap]);
}

// ---- one-off: fc1_w [128][9216 (oc*144+sp)] -> fw1t bf16 [128][9216 (sp*64+oc)] ----
__global__ __launch_bounds__(256) void k_fw1t(const float* __restrict__ w,
    unsigned short* __restrict__ wt) {
  int c = blockIdx.x;
  __shared__ float row[9216];
  int t = threadIdx.x;
  const float* src = w + (size_t)c * 9216;
  for (int i = t; i < 9216; i += 256) row[i] = src[i];
  __syncthreads();
  unsigned short* dst = wt + (size_t)c * 9216;
  for (int k = t; k < 9216; k += 256) {
    int sp = k >> 6, oc = k & 63;
    dst[k] = f2bf(row[oc * 144 + sp]);
  }
}

// ---- one conv2 m-pass: MCNT m-tiles starting at M0, 2 n-frags (np pair) ----
template<int M0, int MCNT>
static __device__ __forceinline__ void conv2_pass(const char* hsb,
    const unsigned short* __restrict__ wt2, const float* __restrict__ b2,
    unsigned short* __restrict__ pp, int col, int g, int wq, int np) {
  int abase[MCNT];
  #pragma unroll
  for (int m = 0; m < MCNT; ++m) {
    int mt = wq * 9 + M0 + m;
    int pr = mt / 3, tc = mt - pr * 3;
    int y = 2 * pr + (col & 1);
    int xx = 8 * tc + (col >> 1);
    abase[m] = (y * 26 + xx) * (H1S_STRIDE * 2) + g * 16;
  }

  f32x4 acc[MCNT][2];
  #pragma unroll
  for (int m = 0; m < MCNT; ++m)
    #pragma unroll
    for (int n = 0; n < 2; ++n)
      acc[m][n] = (f32x4){0.f, 0.f, 0.f, 0.f};

  #pragma unroll
  for (int tap = 0; tap < 9; ++tap) {
    int ky = tap / 3, kx = tap - ky * 3;
    int toff = (ky * 26 + kx) * (H1S_STRIDE * 2);
    short8 bf[2];
    #pragma unroll
    for (int nf = 0; nf < 2; ++nf)
      bf[nf] = *(const short8*)(wt2 + ((size_t)(tap * 4 + np * 2 + nf) * 64 +
                                       (g * 16 + col)) * 8);
    #pragma unroll
    for (int m = 0; m < MCNT; ++m) {
      union { short8 v; uint2 d[2]; } af;
      af.d[0] = *(const uint2*)(hsb + abase[m] + toff);
      af.d[1] = *(const uint2*)(hsb + abase[m] + toff + 8);
      #pragma unroll
      for (int nf = 0; nf < 2; ++nf)
        acc[m][nf] = __builtin_amdgcn_mfma_f32_16x16x32_bf16(af.v, bf[nf], acc[m][nf], 0, 0, 0);
    }
  }

  float bias0 = b2[(np * 2) * 16 + col];
  float bias1 = b2[(np * 2 + 1) * 16 + col];
  #pragma unroll
  for (int m = 0; m < MCNT; ++m) {
    int mt = wq * 9 + M0 + m;
    int pr = mt / 3, tc = mt - pr * 3;
    int sp = pr * 12 + tc * 4 + g;
    f32x4 a0 = acc[m][0];
    f32x4 a1 = acc[m][1];
    float v0 = fmaxf(fmaxf(fmaxf(a0[0], a0[1]), fmaxf(a0[2], a0[3])) + bias0, 0.f);
    float v1 = fmaxf(fmaxf(fmaxf(a1[0], a1[1]), fmaxf(a1[2], a1[3])) + bias1, 0.f);
    unsigned int p01 = pkbf(v0, v1);
    unsigned short* pr0 = pp + sp * 64 + np * 32 + col;
    pr0[0]  = (unsigned short)p01;
    pr0[16] = (unsigned short)(p01 >> 16);
  }
}

// ---- fused conv1+relu+conv2+relu+maxpool -> pooled bf16 [img][144][64] ----
// 512 threads = 8 waves, 2 blocks/CU (51.9 KB LDS). Two conv2 m-passes keep
// peak regs ~95 < 128 (unified VGPR+AGPR cap at 4 waves/EU) -> no spill.
__global__ __launch_bounds__(512, 4) void kc_fused(const float* __restrict__ x,
    const float* __restrict__ w1, const float* __restrict__ b1,
    const unsigned short* __restrict__ wt2, const float* __restrict__ b2,
    unsigned short* __restrict__ pooled) {
  int img = blockIdx.x;
  __shared__ float xs[28 * XS_STRIDE];                            // 3248 B
  __shared__ __align__(16) unsigned short h1s[676 * H1S_STRIDE];  // 48672 B
  int t = threadIdx.x;
  int w = t >> 6, ln = t & 63;

  const float* xp = x + (size_t)img * 784;
  for (int i = t; i < 784; i += 512) {
    int r = i / 28, c = i - r * 28;
    xs[r * XS_STRIDE + c] = xp[i];
  }

  // conv1 weights: 4 channels per wave, wave-uniform
  int wvu = __builtin_amdgcn_readfirstlane(w);
  int c0 = wvu * 4;
  float wr[4][9], br[4];
  #pragma unroll
  for (int o = 0; o < 4; ++o) {
    br[o] = b1[c0 + o];
    #pragma unroll
    for (int q = 0; q < 9; ++q) wr[o][q] = w1[(c0 + o) * 9 + q];
  }
  __syncthreads();

  if (ln < 52) {
    int oy = ln >> 1, x0 = (ln & 1) * 13;
    float win[3][3];
    #pragma unroll
    for (int r = 0; r < 3; ++r) {
      win[r][1] = xs[(oy + r) * XS_STRIDE + x0];
      win[r][2] = xs[(oy + r) * XS_STRIDE + x0 + 1];
    }
    #pragma unroll
    for (int px = 0; px < 13; ++px) {
      #pragma unroll
      for (int r = 0; r < 3; ++r) {
        win[r][0] = win[r][1];
        win[r][1] = win[r][2];
        win[r][2] = xs[(oy + r) * XS_STRIDE + x0 + px + 2];
      }
      unsigned int packed[2];
      #pragma unroll
      for (int o = 0; o < 4; o += 2) {
        float s0 = br[o], s1 = br[o + 1];
        #pragma unroll
        for (int r = 0; r < 3; ++r)
          #pragma unroll
          for (int c = 0; c < 3; ++c) {
            s0 = fmaf(win[r][c], wr[o][r * 3 + c], s0);
            s1 = fmaf(win[r][c], wr[o + 1][r * 3 + c], s1);
          }
        packed[o >> 1] = pkbf(fmaxf(s0, 0.f), fmaxf(s1, 0.f));
      }
      int pos = oy * 26 + x0 + px;
      unsigned short* dst = &h1s[pos * H1S_STRIDE + wvu * 4];
      *(uint2*)dst = make_uint2(packed[0], packed[1]);
    }
  }
  __syncthreads();

  // ---- conv2 + pool, two m-passes ----
  int col = ln & 15;
  int g = (ln >> 4) & 3;
  int wq = w & 3;          // m-group
  int np = w >> 2;         // n-pair

  const char* hsb = (const char*)h1s;
  unsigned short* pp = pooled + (size_t)img * POOLN;

  conv2_pass<0, 5>(hsb, wt2, b2, pp, col, g, wq, np);
  __builtin_amdgcn_sched_barrier(0);
  conv2_pass<5, 4>(hsb, wt2, b2, pp, col, g, wq, np);
}

// ---- fc1 via MFMA, split-K=4: pooled bf16 [nr][9216] @ fw1t bf16 [128][9216]^T
__global__ __launch_bounds__(256) void k3_fc1_mfma(
    const unsigned short* __restrict__ a, const unsigned short* __restrict__ w,
    float* __restrict__ part, int nrpad) {
  __shared__ __align__(16) unsigned short As[2][4096];   // [64][64] bf16 x2
  __shared__ __align__(16) unsigned short Bs[2][8192];   // [128][64] bf16 x2
  int row0 = blockIdx.x * 64;
  int kbase = blockIdx.y * 2304;
  int t = threadIdx.x;
  int wv = t >> 6, l = t & 63;
  int rsub = l >> 3;
  int src_sw = ((l & 7) ^ rsub) << 4;

  const char* abase = (const char*)a + (size_t)row0 * 18432;
  const char* bbase = (const char*)w;

  auto stage = [&](int buf, int step) {
    size_t k0b = (size_t)(kbase + step * 64) * 2;
    #pragma unroll
    for (int i = 0; i < 2; ++i) {
      int c = wv * 2 + i;
      GLL16(abase + (size_t)(c * 8 + rsub) * 18432 + k0b + src_sw,
            (char*)As[buf] + c * 1024);
    }
    #pragma unroll
    for (int i = 0; i < 4; ++i) {
      int c = wv * 4 + i;
      GLL16(bbase + (size_t)(c * 8 + rsub) * 18432 + k0b + src_sw,
            (char*)Bs[buf] + c * 1024);
    }
  };

  int wm = wv >> 1, wn = wv & 1;
  int lr = l & 15, g2 = l >> 4;
  int rdxor = (lr & 7) << 4;

  f32x4 acc[2][4];
  #pragma unroll
  for (int mf = 0; mf < 2; ++mf)
    #pragma unroll
    for (int nf = 0; nf < 4; ++nf)
      acc[mf][nf] = (f32x4){0.f, 0.f, 0.f, 0.f};

  stage(0, 0);
  __syncthreads();
  for (int s = 0; s < 36; ++s) {
    int cur = s & 1;
    if (s < 35) stage(cur ^ 1, s + 1);
    const char* Ab = (const char*)As[cur];
    const char* Bb = (const char*)Bs[cur];
    #pragma unroll
    for (int ksub = 0; ksub < 2; ++ksub) {
      int koff = (ksub * 64 + g2 * 16) ^ rdxor;
      short8 af0 = *(const short8*)(Ab + (wm * 32 + lr) * 128 + koff);
      short8 af1 = *(const short8*)(Ab + (wm * 32 + 16 + lr) * 128 + koff);
      short8 bf[4];
      #pragma unroll
      for (int nf = 0; nf < 4; ++nf)
        bf[nf] = *(const short8*)(Bb + (wn * 64 + nf * 16 + lr) * 128 + koff);
      #pragma unroll
      for (int nf = 0; nf < 4; ++nf) {
        acc[0][nf] = __builtin_amdgcn_mfma_f32_16x16x32_bf16(af0, bf[nf], acc[0][nf], 0, 0, 0);
        acc[1][nf] = __builtin_amdgcn_mfma_f32_16x16x32_bf16(af1, bf[nf], acc[1][nf], 0, 0, 0);
      }
    }
    __syncthreads();
  }

  float* pp = part + (size_t)blockIdx.y * nrpad * 128 + (size_t)row0 * 128;
  #pragma unroll
  for (int mf = 0; mf < 2; ++mf)
    #pragma unroll
    for (int nf = 0; nf < 4; ++nf)
      #pragma unroll
      for (int rr = 0; rr < 4; ++rr) {
        int r = wm * 32 + mf * 16 + g2 * 4 + rr;
        int c = wn * 64 + nf * 16 + lr;
        pp[r * 128 + c] = acc[mf][nf][rr];
      }
}

// ---- reduce 4 split-K partials + bias + relu -> f1o fp32 [nr][128] ----
__global__ __launch_bounds__(256) void k_red(const float* __restrict__ part,
    const float* __restrict__ bias, float* __restrict__ f1o, int nr, int nrpad) {
  int i = blockIdx.x * 256 + threadIdx.x;
  if (i >= nr * 128) return;
  size_t stride = (size_t)nrpad * 128;
  float s = part[i] + part[stride + i] + part[2 * stride + i] + part[3 * stride + i];
  f1o[i] = fmaxf(s + bias[i & 127], 0.f);
}

// ---- fc2 ----
__global__ __launch_bounds__(256) void k4_fc2(const float* __restrict__ h,
    const float* __restrict__ w, const float* __restrict__ bias,
    float* __restrict__ out, int nr) {
  int idx = blockIdx.x * 256 + threadIdx.x;
  if (idx >= nr * 10) return;
  int b = idx / 10;
  int j = idx - b * 10;
  const float4* hp = (const float4*)(h + (size_t)b * 128);
  const float4* wp = (const float4*)(w + (size_t)j * 128);
  float s = 0.f;
  #pragma unroll
  for (int q = 0; q < 32; ++q) {
    float4 hv = hp[q];
    float4 wv = wp[q];
    s = fmaf(hv.x, wv.x, s);
    s = fmaf(hv.y, wv.y, s);
    s = fmaf(hv.z, wv.z, s);
    s = fmaf(hv.w, wv.w, s);
  }
  out[idx] = s + bias[j];
}

extern "C" void kernel_launch(void* const* d_in, const int* in_sizes, int n_in,
                              void* d_out, int out_size, void* d_ws, size_t ws_size,
                              hipStream_t stream) {
  const float* x   = (const float*)d_in[0];
  const float* w1  = (const float*)d_in[1];
  const float* b1  = (const float*)d_in[2];
  const float* w2  = (const float*)d_in[3];
  const float* b2  = (const float*)d_in[4];
  const float* fw1 = (const float*)d_in[5];
  const float* fb1 = (const float*)d_in[6];
  const float* fw2 = (const float*)d_in[7];
  const float* fb2 = (const float*)d_in[8];
  float* out = (float*)d_out;

  const int B = in_sizes[0] / 784;

  unsigned short* wt2 = (unsigned short*)d_ws;                        // 36864 B
  unsigned short* fw1t = (unsigned short*)((char*)d_ws + WT2_BYTES);  // 2359296 B
  const size_t carve = WT2_BYTES + (size_t)9216 * 128 * 2;
  char* base = (char*)d_ws + carve;
  size_t avail = (ws_size > carve) ? ws_size - carve : 0;
  const size_t per_img = (size_t)POOLN * 2 + 512 + 2048;
  int Bc = (int)(avail / per_img);
  if (Bc > B) Bc = B;
  Bc &= ~63;
  if (Bc < 64) Bc = 64;

  unsigned short* pooled = (unsigned short*)base;
  float* f1o = (float*)(base + (size_t)Bc * (POOLN * 2));
  float* part = (float*)(base + (size_t)Bc * (POOLN * 2 + 512));

  k_wt2<<<(WT2_ELEMS + 255) / 256, 256, 0, stream>>>(w2, wt2);
  k_fw1t<<<128, 256, 0, stream>>>(fw1, fw1t);

  for (int i0 = 0; i0 < B; i0 += Bc) {
    int nr = (B - i0 < Bc) ? (B - i0) : Bc;
    int mtiles = (nr + 63) / 64;
    int nrpad = mtiles * 64;
    kc_fused<<<nr, 512, 0, stream>>>(x + (size_t)i0 * 784, w1, b1, wt2, b2, pooled);
    k3_fc1_mfma<<<dim3(mtiles, 4), 256, 0, stream>>>(pooled, fw1t, part, nrpad);
    k_red<<<(nr * 128 + 255) / 256, 256, 0, stream>>>(part, fb1, f1o, nr, nrpad);
    k4_fc2<<<(nr * 10 + 255) / 256, 256, 0, stream>>>(f1o, fw2, fb2,
                                                      out + (size_t)i0 * 10, nr);
  }
}

// Round 9
// 156.035 us; speedup vs baseline: 1.2274x; 1.2274x over previous
//
#include <hip/hip_runtime.h>
#include <hip/hip_bf16.h>
#include <string.h>

using short8 = __attribute__((ext_vector_type(8))) short;
using f32x4  = __attribute__((ext_vector_type(4))) float;

#define POOLN     9216       // 144*64 elements (bf16) per image
#define FC1N      128
#define WT2_ELEMS 18432      // 36*64*8
#define WT2_BYTES 36864
#define H1S_STRIDE 36        // shorts per position row (72 B): <=2-way conflicts
#define XS_STRIDE  29        // floats per x row (odd -> conflict-free)

#define GLL16(gp, lp) __builtin_amdgcn_global_load_lds( \
    (const __attribute__((address_space(1))) void*)(gp), \
    (__attribute__((address_space(3))) void*)(lp), 16, 0, 0)

static __device__ __forceinline__ unsigned short f2bf(float f) {
  unsigned int u = __builtin_bit_cast(unsigned int, f);
  unsigned int r = (u + 0x7FFFu + ((u >> 16) & 1u)) >> 16;
  return (unsigned short)r;
}

// packed RNE pair convert -> v_cvt_pk_bf16_f32 (compiler-emitted, m240)
static __device__ __forceinline__ unsigned int pkbf(float lo, float hi) {
  __hip_bfloat162 h2 = __float22bfloat162_rn(make_float2(lo, hi));
  unsigned int r;
  memcpy(&r, &h2, sizeof(r));
  return r;
}

// ---- one-off: w2 fp32 [64][32][9] -> wt2 bf16 fragment order [(tap*4+n)][lane][8]
__global__ __launch_bounds__(256) void k_wt2(const float* __restrict__ w2,
    unsigned short* __restrict__ wt2) {
  int idx = blockIdx.x * 256 + threadIdx.x;
  if (idx >= WT2_ELEMS) return;
  int j = idx & 7;
  int l = (idx >> 3) & 63;
  int tn = idx >> 9;            // 0..35
  int tap = tn >> 2, n = tn & 3;
  int oc = n * 16 + (l & 15);
  int ic = (l >> 4) * 8 + j;
  wt2[idx] = f2bf(w2[oc * 288 + ic * 9 + tap]);
}

// ---- one-off: fc1_w [128][9216 (oc*144+sp)] -> fw1t bf16 [128][9216 (sp*64+oc)] ----
__global__ __launch_bounds__(256) void k_fw1t(const float* __restrict__ w,
    unsigned short* __restrict__ wt) {
  int c = blockIdx.x;
  __shared__ float row[9216];
  int t = threadIdx.x;
  const float* src = w + (size_t)c * 9216;
  for (int i = t; i < 9216; i += 256) row[i] = src[i];
  __syncthreads();
  unsigned short* dst = wt + (size_t)c * 9216;
  for (int k = t; k < 9216; k += 256) {
    int sp = k >> 6, oc = k & 63;
    dst[k] = f2bf(row[oc * 144 + sp]);
  }
}

// ---- fused conv1+relu+conv2+relu+maxpool -> pooled bf16 [img][144][64] ----
// R4-proven register shape: 256 thr, 4 waves, acc[9][4], launch_bounds(256,2).
// New: h1s stride 72 B, transposed conv1 lane map (lane = column, slide rows),
// padded xs. LDS 51.9 KB.
__global__ __launch_bounds__(256, 2) void kc_fused(const float* __restrict__ x,
    const float* __restrict__ w1, const float* __restrict__ b1,
    const unsigned short* __restrict__ wt2, const float* __restrict__ b2,
    unsigned short* __restrict__ pooled) {
  int img = blockIdx.x;
  __shared__ float xs[28 * XS_STRIDE];                            // 3248 B
  __shared__ __align__(16) unsigned short h1s[676 * H1S_STRIDE];  // 48672 B
  int t = threadIdx.x;
  int wv = t >> 6, ln = t & 63;

  const float* xp = x + (size_t)img * 784;
  for (int i = t; i < 784; i += 256) {
    int r = i / 28, c = i - r * 28;
    xs[r * XS_STRIDE + c] = xp[i];
  }

  // conv1 weights: 8 channels per wave, wave-uniform address (scalar loads)
  int wvu = __builtin_amdgcn_readfirstlane(wv);
  float wr[8][9], br[8];
  #pragma unroll
  for (int o = 0; o < 8; ++o) {
    br[o] = b1[wvu * 8 + o];
    #pragma unroll
    for (int q = 0; q < 9; ++q) wr[o][q] = w1[(wvu * 8 + o) * 9 + q];
  }
  __syncthreads();

  // transposed map: lane -> output column xcol, iterate 13 rows vertically
  if (ln < 52) {
    int half = (ln >= 26);
    int xcol = ln - half * 26;          // 0..25
    int y0 = half * 13;
    float win[3][3];
    #pragma unroll
    for (int c = 0; c < 3; ++c) {
      win[1][c] = xs[(y0 + 0) * XS_STRIDE + xcol + c];
      win[2][c] = xs[(y0 + 1) * XS_STRIDE + xcol + c];
    }
    #pragma unroll
    for (int i = 0; i < 13; ++i) {
      #pragma unroll
      for (int c = 0; c < 3; ++c) {
        win[0][c] = win[1][c];
        win[1][c] = win[2][c];
        win[2][c] = xs[(y0 + i + 2) * XS_STRIDE + xcol + c];
      }
      unsigned int packed[4];
      #pragma unroll
      for (int o = 0; o < 8; o += 2) {
        float s0 = br[o], s1 = br[o + 1];
        #pragma unroll
        for (int r = 0; r < 3; ++r)
          #pragma unroll
          for (int c = 0; c < 3; ++c) {
            s0 = fmaf(win[r][c], wr[o][r * 3 + c], s0);
            s1 = fmaf(win[r][c], wr[o + 1][r * 3 + c], s1);
          }
        packed[o >> 1] = pkbf(fmaxf(s0, 0.f), fmaxf(s1, 0.f));
      }
      int pos = (y0 + i) * 26 + xcol;
      uint4 v = {packed[0], packed[1], packed[2], packed[3]};
      *(uint4*)&h1s[pos * H1S_STRIDE + wv * 8] = v;
    }
  }
  __syncthreads();

  // ---- conv2 + pool ----
  int col = ln & 15;
  int g = (ln >> 4) & 3;

  int abase[9];
  #pragma unroll
  for (int m = 0; m < 9; ++m) {
    int mt = wv * 9 + m;
    int pr = mt / 3, tc = mt - pr * 3;
    int y = 2 * pr + (col & 1);
    int xx = 8 * tc + (col >> 1);
    abase[m] = (y * 26 + xx) * (H1S_STRIDE * 2) + g * 16;
  }

  f32x4 acc[9][4];
  #pragma unroll
  for (int m = 0; m < 9; ++m)
    #pragma unroll
    for (int n = 0; n < 4; ++n)
      acc[m][n] = (f32x4){0.f, 0.f, 0.f, 0.f};

  const char* hsb = (const char*)h1s;
  #pragma unroll
  for (int tap = 0; tap < 9; ++tap) {
    int ky = tap / 3, kx = tap - ky * 3;
    int toff = (ky * 26 + kx) * (H1S_STRIDE * 2);
    short8 bf[4];
    #pragma unroll
    for (int n = 0; n < 4; ++n)
      bf[n] = *(const short8*)(wt2 + ((size_t)(tap * 4 + n) * 64 + ln) * 8);
    #pragma unroll
    for (int m = 0; m < 9; ++m) {
      union { short8 v; uint2 d[2]; } af;
      af.d[0] = *(const uint2*)(hsb + abase[m] + toff);
      af.d[1] = *(const uint2*)(hsb + abase[m] + toff + 8);
      #pragma unroll
      for (int n = 0; n < 4; ++n)
        acc[m][n] = __builtin_amdgcn_mfma_f32_16x16x32_bf16(af.v, bf[n], acc[m][n], 0, 0, 0);
    }
  }

  float bias[4];
  #pragma unroll
  for (int n = 0; n < 4; ++n) bias[n] = b2[n * 16 + col];
  unsigned short* pp = pooled + (size_t)img * POOLN;
  #pragma unroll
  for (int m = 0; m < 9; ++m) {
    int mt = wv * 9 + m;
    int pr = mt / 3, tc = mt - pr * 3;
    int sp = pr * 12 + tc * 4 + g;
    float rv[4];
    #pragma unroll
    for (int n = 0; n < 4; ++n) {
      f32x4 a = acc[m][n];
      float v = fmaxf(fmaxf(a[0], a[1]), fmaxf(a[2], a[3]));
      rv[n] = fmaxf(v + bias[n], 0.f);
    }
    unsigned int p01 = pkbf(rv[0], rv[1]);
    unsigned int p23 = pkbf(rv[2], rv[3]);
    unsigned short* pr0 = pp + sp * 64 + col;
    pr0[0]  = (unsigned short)p01;
    pr0[16] = (unsigned short)(p01 >> 16);
    pr0[32] = (unsigned short)p23;
    pr0[48] = (unsigned short)(p23 >> 16);
  }
}

// ---- fc1 via MFMA, split-K=4: pooled bf16 [nr][9216] @ fw1t bf16 [128][9216]^T
__global__ __launch_bounds__(256) void k3_fc1_mfma(
    const unsigned short* __restrict__ a, const unsigned short* __restrict__ w,
    float* __restrict__ part, int nrpad) {
  __shared__ __align__(16) unsigned short As[2][4096];   // [64][64] bf16 x2
  __shared__ __align__(16) unsigned short Bs[2][8192];   // [128][64] bf16 x2
  int row0 = blockIdx.x * 64;
  int kbase = blockIdx.y * 2304;
  int t = threadIdx.x;
  int wv = t >> 6, l = t & 63;
  int rsub = l >> 3;
  int src_sw = ((l & 7) ^ rsub) << 4;

  const char* abase = (const char*)a + (size_t)row0 * 18432;
  const char* bbase = (const char*)w;

  auto stage = [&](int buf, int step) {
    size_t k0b = (size_t)(kbase + step * 64) * 2;
    #pragma unroll
    for (int i = 0; i < 2; ++i) {
      int c = wv * 2 + i;
      GLL16(abase + (size_t)(c * 8 + rsub) * 18432 + k0b + src_sw,
            (char*)As[buf] + c * 1024);
    }
    #pragma unroll
    for (int i = 0; i < 4; ++i) {
      int c = wv * 4 + i;
      GLL16(bbase + (size_t)(c * 8 + rsub) * 18432 + k0b + src_sw,
            (char*)Bs[buf] + c * 1024);
    }
  };

  int wm = wv >> 1, wn = wv & 1;
  int lr = l & 15, g2 = l >> 4;
  int rdxor = (lr & 7) << 4;

  f32x4 acc[2][4];
  #pragma unroll
  for (int mf = 0; mf < 2; ++mf)
    #pragma unroll
    for (int nf = 0; nf < 4; ++nf)
      acc[mf][nf] = (f32x4){0.f, 0.f, 0.f, 0.f};

  stage(0, 0);
  __syncthreads();
  for (int s = 0; s < 36; ++s) {
    int cur = s & 1;
    if (s < 35) stage(cur ^ 1, s + 1);
    const char* Ab = (const char*)As[cur];
    const char* Bb = (const char*)Bs[cur];
    #pragma unroll
    for (int ksub = 0; ksub < 2; ++ksub) {
      int koff = (ksub * 64 + g2 * 16) ^ rdxor;
      short8 af0 = *(const short8*)(Ab + (wm * 32 + lr) * 128 + koff);
      short8 af1 = *(const short8*)(Ab + (wm * 32 + 16 + lr) * 128 + koff);
      short8 bf[4];
      #pragma unroll
      for (int nf = 0; nf < 4; ++nf)
        bf[nf] = *(const short8*)(Bb + (wn * 64 + nf * 16 + lr) * 128 + koff);
      #pragma unroll
      for (int nf = 0; nf < 4; ++nf) {
        acc[0][nf] = __builtin_amdgcn_mfma_f32_16x16x32_bf16(af0, bf[nf], acc[0][nf], 0, 0, 0);
        acc[1][nf] = __builtin_amdgcn_mfma_f32_16x16x32_bf16(af1, bf[nf], acc[1][nf], 0, 0, 0);
      }
    }
    __syncthreads();
  }

  float* pp = part + (size_t)blockIdx.y * nrpad * 128 + (size_t)row0 * 128;
  #pragma unroll
  for (int mf = 0; mf < 2; ++mf)
    #pragma unroll
    for (int nf = 0; nf < 4; ++nf)
      #pragma unroll
      for (int rr = 0; rr < 4; ++rr) {
        int r = wm * 32 + mf * 16 + g2 * 4 + rr;
        int c = wn * 64 + nf * 16 + lr;
        pp[r * 128 + c] = acc[mf][nf][rr];
      }
}

// ---- reduce 4 split-K partials + bias + relu -> f1o fp32 [nr][128] ----
__global__ __launch_bounds__(256) void k_red(const float* __restrict__ part,
    const float* __restrict__ bias, float* __restrict__ f1o, int nr, int nrpad) {
  int i = blockIdx.x * 256 + threadIdx.x;
  if (i >= nr * 128) return;
  size_t stride = (size_t)nrpad * 128;
  float s = part[i] + part[stride + i] + part[2 * stride + i] + part[3 * stride + i];
  f1o[i] = fmaxf(s + bias[i & 127], 0.f);
}

// ---- fc2 ----
__global__ __launch_bounds__(256) void k4_fc2(const float* __restrict__ h,
    const float* __restrict__ w, const float* __restrict__ bias,
    float* __restrict__ out, int nr) {
  int idx = blockIdx.x * 256 + threadIdx.x;
  if (idx >= nr * 10) return;
  int b = idx / 10;
  int j = idx - b * 10;
  const float4* hp = (const float4*)(h + (size_t)b * 128);
  const float4* wp = (const float4*)(w + (size_t)j * 128);
  float s = 0.f;
  #pragma unroll
  for (int q = 0; q < 32; ++q) {
    float4 hv = hp[q];
    float4 wv = wp[q];
    s = fmaf(hv.x, wv.x, s);
    s = fmaf(hv.y, wv.y, s);
    s = fmaf(hv.z, wv.z, s);
    s = fmaf(hv.w, wv.w, s);
  }
  out[idx] = s + bias[j];
}

extern "C" void kernel_launch(void* const* d_in, const int* in_sizes, int n_in,
                              void* d_out, int out_size, void* d_ws, size_t ws_size,
                              hipStream_t stream) {
  const float* x   = (const float*)d_in[0];
  const float* w1  = (const float*)d_in[1];
  const float* b1  = (const float*)d_in[2];
  const float* w2  = (const float*)d_in[3];
  const float* b2  = (const float*)d_in[4];
  const float* fw1 = (const float*)d_in[5];
  const float* fb1 = (const float*)d_in[6];
  const float* fw2 = (const float*)d_in[7];
  const float* fb2 = (const float*)d_in[8];
  float* out = (float*)d_out;

  const int B = in_sizes[0] / 784;

  unsigned short* wt2 = (unsigned short*)d_ws;                        // 36864 B
  unsigned short* fw1t = (unsigned short*)((char*)d_ws + WT2_BYTES);  // 2359296 B
  const size_t carve = WT2_BYTES + (size_t)9216 * 128 * 2;
  char* base = (char*)d_ws + carve;
  size_t avail = (ws_size > carve) ? ws_size - carve : 0;
  const size_t per_img = (size_t)POOLN * 2 + 512 + 2048;
  int Bc = (int)(avail / per_img);
  if (Bc > B) Bc = B;
  Bc &= ~63;
  if (Bc < 64) Bc = 64;

  unsigned short* pooled = (unsigned short*)base;
  float* f1o = (float*)(base + (size_t)Bc * (POOLN * 2));
  float* part = (float*)(base + (size_t)Bc * (POOLN * 2 + 512));

  k_wt2<<<(WT2_ELEMS + 255) / 256, 256, 0, stream>>>(w2, wt2);
  k_fw1t<<<128, 256, 0, stream>>>(fw1, fw1t);

  for (int i0 = 0; i0 < B; i0 += Bc) {
    int nr = (B - i0 < Bc) ? (B - i0) : Bc;
    int mtiles = (nr + 63) / 64;
    int nrpad = mtiles * 64;
    kc_fused<<<nr, 256, 0, stream>>>(x + (size_t)i0 * 784, w1, b1, wt2, b2, pooled);
    k3_fc1_mfma<<<dim3(mtiles, 4), 256, 0, stream>>>(pooled, fw1t, part, nrpad);
    k_red<<<(nr * 128 + 255) / 256, 256, 0, stream>>>(part, fb1, f1o, nr, nrpad);
    k4_fc2<<<(nr * 10 + 255) / 256, 256, 0, stream>>>(f1o, fw2, fb2,
                                                      out + (size_t)i0 * 10, nr);
  }
}